// Round 8
// baseline (252.014 us; speedup 1.0000x reference)
//
#include <hip/hip_runtime.h>
#include <math.h>

#define BB    16
#define VN    256
#define QN    256
#define VD    512
#define QD    768
#define HK    1536
#define HDIM  512

typedef _Float16 half8 __attribute__((ext_vector_type(8)));
typedef _Float16 half4 __attribute__((ext_vector_type(4)));
typedef float f32x4 __attribute__((ext_vector_type(4)));

// ---------------------------------------------------------------------------
// fused fp32->f16 conversion + zero-row mask for BOTH v and q in one launch.
// blockIdx.y: 0 -> v (D=512), 1 -> q (D=768). One wave per row, 4 rows/block.
// ---------------------------------------------------------------------------
__global__ __launch_bounds__(256) void conv_mask2(
    const float* __restrict__ v, const float* __restrict__ q,
    _Float16* __restrict__ v16, _Float16* __restrict__ q16,
    float* __restrict__ vz, float* __restrict__ qz) {
    int which = blockIdx.y;
    const float* src = which ? q : v;
    _Float16* dst = which ? q16 : v16;
    float* outz = which ? qz : vz;
    int D = which ? QD : VD;
    int w = threadIdx.x >> 6, ln = threadIdx.x & 63;
    int row = blockIdx.x * 4 + w;
    const float* p = src + (size_t)row * D;
    _Float16* d = dst + (size_t)row * D;
    float s = 0.f;
    for (int c = ln * 4; c < D; c += 256) {
        float4 x = *(const float4*)(p + c);
        s += fabsf(x.x) + fabsf(x.y) + fabsf(x.z) + fabsf(x.w);
        half4 hh = {(_Float16)x.x, (_Float16)x.y, (_Float16)x.z, (_Float16)x.w};
        *(half4*)(d + c) = hh;
    }
    for (int off = 32; off > 0; off >>= 1) s += __shfl_down(s, off);
    if (ln == 0) outz[row] = (s == 0.f) ? 1.f : 0.f;
}

// ---------------------------------------------------------------------------
// fp32 -> f16 for both weight matrices in one launch (y=0 Wv, y=1 Wq)
// ---------------------------------------------------------------------------
__global__ __launch_bounds__(256) void conv_w2(
    const float* __restrict__ Wv, _Float16* __restrict__ Wv16, int n4v,
    const float* __restrict__ Wq, _Float16* __restrict__ Wq16, int n4q) {
    const float* src = blockIdx.y ? Wq : Wv;
    _Float16* dst = blockIdx.y ? Wq16 : Wv16;
    int n4 = blockIdx.y ? n4q : n4v;
    int i = blockIdx.x * 256 + threadIdx.x;
    if (i < n4) {
        float4 x = ((const float4*)src)[i];
        half4 h = {(_Float16)x.x, (_Float16)x.y, (_Float16)x.z, (_Float16)x.w};
        ((half4*)dst)[i] = h;
    }
}

// hm fp32 [8][HK] -> hs16 [9][HK] f16, row 8 = sum of rows 0..7
__global__ __launch_bounds__(256) void conv_hm9(const float* __restrict__ hm,
                                                _Float16* __restrict__ hs16) {
    int k = blockIdx.x * 256 + threadIdx.x;
    if (k >= HK) return;
    float s = 0.f;
#pragma unroll
    for (int h = 0; h < 8; ++h) {
        float x = hm[h * HK + k];
        s += x;
        hs16[h * HK + k] = (_Float16)x;
    }
    hs16[8 * HK + k] = (_Float16)s;
}

// ---------------------------------------------------------------------------
// Projection GEMM, double-buffered single-barrier pipeline:
// C16[m,n] = (f16) relu(sum_k A[m,k]*W[n,k] + b[n])
// Block 64m x 64n, 128 thr = 2 waves (wave 32m x 64n), BK=64.
// iter it: regs hold tile it+1 -> write buf cur^1; issue loads tile it+2;
// compute buf cur; ONE barrier at loop end.
// ---------------------------------------------------------------------------
__global__ __launch_bounds__(128) void proj_db(
    const _Float16* __restrict__ Ain, const _Float16* __restrict__ W16,
    const float* __restrict__ bias, _Float16* __restrict__ C16, int K) {
    __shared__ _Float16 As[2 * 4096];
    __shared__ _Float16 Bs[2 * 4096];
    int m0 = blockIdx.y * 64, n0 = blockIdx.x * 64;
    int t = threadIdx.x;
    int w = t >> 6, ln = t & 63, quad = ln >> 4, r16 = ln & 15;
    int arow = t >> 3, aseg = t & 7;
    int sg = aseg ^ (arow & 7);
    const _Float16* ApG = Ain + (size_t)(m0 + arow) * K + aseg * 8;
    const _Float16* BpG = W16 + (size_t)(n0 + arow) * K + aseg * 8;
    int NIT = K >> 6;
    half8 ra[4], rb[4];
    // prologue: tile 0 -> buf0
#pragma unroll
    for (int c = 0; c < 4; ++c) {
        ra[c] = *(const half8*)(ApG + (size_t)c * 16 * K);
        rb[c] = *(const half8*)(BpG + (size_t)c * 16 * K);
    }
#pragma unroll
    for (int c = 0; c < 4; ++c) {
        *(half8*)&As[(c * 16 + arow) * 64 + sg * 8] = ra[c];
        *(half8*)&Bs[(c * 16 + arow) * 64 + sg * 8] = rb[c];
    }
    // load tile 1
#pragma unroll
    for (int c = 0; c < 4; ++c) {
        ra[c] = *(const half8*)(ApG + (size_t)c * 16 * K + 64);
        rb[c] = *(const half8*)(BpG + (size_t)c * 16 * K + 64);
    }
    __syncthreads();
    f32x4 acc[2][4] = {};
    for (int it = 0; it < NIT; ++it) {
        int cur = it & 1;
        _Float16* Ac = &As[cur * 4096];
        _Float16* Bc = &Bs[cur * 4096];
        if (it + 1 < NIT) {
            _Float16* An = &As[(cur ^ 1) * 4096];
            _Float16* Bn = &Bs[(cur ^ 1) * 4096];
#pragma unroll
            for (int c = 0; c < 4; ++c) {
                *(half8*)&An[(c * 16 + arow) * 64 + sg * 8] = ra[c];
                *(half8*)&Bn[(c * 16 + arow) * 64 + sg * 8] = rb[c];
            }
        }
        if (it + 2 < NIT) {
            int kn = (it + 2) * 64;
#pragma unroll
            for (int c = 0; c < 4; ++c) {
                ra[c] = *(const half8*)(ApG + (size_t)c * 16 * K + kn);
                rb[c] = *(const half8*)(BpG + (size_t)c * 16 * K + kn);
            }
        }
#pragma unroll
        for (int kc = 0; kc < 2; ++kc) {
            half8 af[2], bf[4];
#pragma unroll
            for (int fi = 0; fi < 2; ++fi) {
                int rl = w * 32 + fi * 16 + r16;
                af[fi] = *(const half8*)&Ac[rl * 64 + ((kc * 4 + quad) ^ (rl & 7)) * 8];
            }
#pragma unroll
            for (int fj = 0; fj < 4; ++fj) {
                int rl = fj * 16 + r16;
                bf[fj] = *(const half8*)&Bc[rl * 64 + ((kc * 4 + quad) ^ (rl & 7)) * 8];
            }
#pragma unroll
            for (int fi = 0; fi < 2; ++fi)
#pragma unroll
                for (int fj = 0; fj < 4; ++fj)
                    acc[fi][fj] = __builtin_amdgcn_mfma_f32_16x16x32_f16(
                        af[fi], bf[fj], acc[fi][fj], 0, 0, 0);
        }
        __syncthreads();
    }
#pragma unroll
    for (int fi = 0; fi < 2; ++fi) {
#pragma unroll
        for (int r = 0; r < 4; ++r) {
            int m = m0 + w * 32 + fi * 16 + quad * 4 + r;
#pragma unroll
            for (int fj = 0; fj < 4; ++fj) {
                int n = n0 + fj * 16 + r16;
                float x = acc[fi][fj][r] + bias[n];
                C16[(size_t)m * HK + n] = (_Float16)fmaxf(x, 0.f);
            }
        }
    }
}

// ---------------------------------------------------------------------------
// att: 3 heads per wave, double-buffered single-barrier K-loop.
// Block 64i x 64j, 128 thr = 2 waves (wave 32i x 64j x 3 heads).
// z = b*3 + head_group. h<8 -> att_out fp32; h==8 -> A16 f16.
// ---------------------------------------------------------------------------
__global__ __launch_bounds__(128) void att_db(
    const _Float16* __restrict__ v16, const _Float16* __restrict__ q16,
    const _Float16* __restrict__ hs16, const float* __restrict__ hb,
    const float* __restrict__ vz, const float* __restrict__ qz,
    float* __restrict__ att_out, _Float16* __restrict__ A16) {
    __shared__ _Float16 As[2 * 4096];
    __shared__ _Float16 Bs[2 * 4096];
    __shared__ _Float16 Hl[3 * HK];
    int z = blockIdx.z;
    int b = z / 3, hg = z - b * 3;
    int h0 = hg * 3;
    int i0 = blockIdx.y * 64, j0 = blockIdx.x * 64;
    int t = threadIdx.x;
    int w = t >> 6, ln = t & 63, quad = ln >> 4, r16 = ln & 15;
    int arow = t >> 3, aseg = t & 7;
    int sg = aseg ^ (arow & 7);
    // stage hm rows h0..h0+2 (9 KB), fenced by the prologue barrier
    for (int u = t * 8; u < 3 * HK; u += 128 * 8)
        *(half8*)&Hl[u] = *(const half8*)(hs16 + (size_t)h0 * HK + u);
    const _Float16* ApG = v16 + (size_t)b * VN * HK + (size_t)(i0 + arow) * HK + aseg * 8;
    const _Float16* BpG = q16 + (size_t)b * QN * HK + (size_t)(j0 + arow) * HK + aseg * 8;
    half8 ra[4], rb[4];
    // prologue: tile 0 -> buf0
#pragma unroll
    for (int c = 0; c < 4; ++c) {
        ra[c] = *(const half8*)(ApG + (size_t)c * 16 * HK);
        rb[c] = *(const half8*)(BpG + (size_t)c * 16 * HK);
    }
#pragma unroll
    for (int c = 0; c < 4; ++c) {
        *(half8*)&As[(c * 16 + arow) * 64 + sg * 8] = ra[c];
        *(half8*)&Bs[(c * 16 + arow) * 64 + sg * 8] = rb[c];
    }
    // load tile 1
#pragma unroll
    for (int c = 0; c < 4; ++c) {
        ra[c] = *(const half8*)(ApG + (size_t)c * 16 * HK + 64);
        rb[c] = *(const half8*)(BpG + (size_t)c * 16 * HK + 64);
    }
    __syncthreads();
    f32x4 acc[3][2][4] = {};
    for (int it = 0; it < 24; ++it) {
        int cur = it & 1;
        _Float16* Ac = &As[cur * 4096];
        _Float16* Bc = &Bs[cur * 4096];
        if (it + 1 < 24) {
            _Float16* An = &As[(cur ^ 1) * 4096];
            _Float16* Bn = &Bs[(cur ^ 1) * 4096];
#pragma unroll
            for (int c = 0; c < 4; ++c) {
                *(half8*)&An[(c * 16 + arow) * 64 + sg * 8] = ra[c];
                *(half8*)&Bn[(c * 16 + arow) * 64 + sg * 8] = rb[c];
            }
        }
        if (it + 2 < 24) {
            int kn = (it + 2) * 64;
#pragma unroll
            for (int c = 0; c < 4; ++c) {
                ra[c] = *(const half8*)(ApG + (size_t)c * 16 * HK + kn);
                rb[c] = *(const half8*)(BpG + (size_t)c * 16 * HK + kn);
            }
        }
        int kb = it * 64;
#pragma unroll
        for (int kc = 0; kc < 2; ++kc) {
            half8 af[2], bf[4];
#pragma unroll
            for (int fi = 0; fi < 2; ++fi) {
                int rl = w * 32 + fi * 16 + r16;
                af[fi] = *(const half8*)&Ac[rl * 64 + ((kc * 4 + quad) ^ (rl & 7)) * 8];
            }
#pragma unroll
            for (int fj = 0; fj < 4; ++fj) {
                int rl = fj * 16 + r16;
                bf[fj] = *(const half8*)&Bc[rl * 64 + ((kc * 4 + quad) ^ (rl & 7)) * 8];
            }
#pragma unroll
            for (int hh = 0; hh < 3; ++hh) {
                half8 hmv = *(const half8*)&Hl[hh * HK + kb + (kc * 4 + quad) * 8];
#pragma unroll
                for (int fi = 0; fi < 2; ++fi) {
                    half8 am = af[fi] * hmv;
#pragma unroll
                    for (int fj = 0; fj < 4; ++fj)
                        acc[hh][fi][fj] = __builtin_amdgcn_mfma_f32_16x16x32_f16(
                            am, bf[fj], acc[hh][fi][fj], 0, 0, 0);
                }
            }
        }
        __syncthreads();
    }
#pragma unroll
    for (int hh = 0; hh < 3; ++hh) {
        int h = h0 + hh;
        float hbv;
        if (h < 8) {
            hbv = hb[h];
        } else {
            hbv = 0.f;
#pragma unroll
            for (int x = 0; x < 8; ++x) hbv += hb[x];
        }
        if (h < 8) {
            float* outb = att_out + ((size_t)(b * 8 + h)) * VN * QN;
#pragma unroll
            for (int fi = 0; fi < 2; ++fi) {
#pragma unroll
                for (int r = 0; r < 4; ++r) {
                    int i = i0 + w * 32 + fi * 16 + quad * 4 + r;
                    float vm = vz[b * VN + i];
#pragma unroll
                    for (int fj = 0; fj < 4; ++fj) {
                        int j = j0 + fj * 16 + r16;
                        float x = acc[hh][fi][fj][r] + hbv;
                        if (vm != 0.f || qz[b * QN + j] != 0.f) x = -INFINITY;
                        outb[(size_t)i * QN + j] = x;
                    }
                }
            }
        } else {
            _Float16* Ab = A16 + (size_t)b * VN * QN;
#pragma unroll
            for (int fi = 0; fi < 2; ++fi) {
#pragma unroll
                for (int r = 0; r < 4; ++r) {
                    int i = i0 + w * 32 + fi * 16 + quad * 4 + r;
                    float vm = vz[b * VN + i];
#pragma unroll
                    for (int fj = 0; fj < 4; ++fj) {
                        int j = j0 + fj * 16 + r16;
                        float x = acc[hh][fi][fj][r] + hbv;
                        if (vm != 0.f || qz[b * QN + j] != 0.f) x = -INFINITY;
                        Ab[(size_t)i * QN + j] = (_Float16)x;
                    }
                }
            }
        }
    }
}

// ---------------------------------------------------------------------------
// q16t[b][k][j] = q16[b][j][k]  (per-batch transpose, 32j x 64k LDS tiles)
// ---------------------------------------------------------------------------
__global__ __launch_bounds__(256) void transpose_q16(const _Float16* __restrict__ q16,
                                                     _Float16* __restrict__ q16t) {
    __shared__ _Float16 Ls[32][72];
    int b = blockIdx.z;
    int k0 = blockIdx.x * 64, j0 = blockIdx.y * 32;
    int t = threadIdx.x;
    const _Float16* src = q16 + (size_t)b * QN * HK;
    int tj = t >> 3, tk = (t & 7) * 8;
    half8 vv = *(const half8*)(src + (size_t)(j0 + tj) * HK + k0 + tk);
#pragma unroll
    for (int e = 0; e < 8; ++e) Ls[tj][tk + e] = vv[e];
    __syncthreads();
    int ok = t >> 2, oj = (t & 3) * 8;
    half8 ov;
#pragma unroll
    for (int e = 0; e < 8; ++e) ov[e] = Ls[oj + e][ok];
    *(half8*)(q16t + (size_t)b * HK * QN + (size_t)(k0 + ok) * QN + j0 + oj) = ov;
}

// ---------------------------------------------------------------------------
// lk[b,k] = sum_i v16[b,i,k] * (sum_j A16[b,i,j] * q16t[b,k,j])
// ---------------------------------------------------------------------------
__global__ __launch_bounds__(256) void t_lk_mfma(
    const _Float16* __restrict__ A16, const _Float16* __restrict__ q16t,
    const _Float16* __restrict__ v16, float* __restrict__ lk) {
    __shared__ _Float16 As[256 * 32];
    __shared__ _Float16 Bs[64 * 32];
    __shared__ float red[16][64];
    int b = blockIdx.y;
    int k0 = blockIdx.x * 64;
    int t = threadIdx.x;
    int w = t >> 6, ln = t & 63, quad = ln >> 4, r16 = ln & 15;
    const _Float16* Ab = A16 + (size_t)b * VN * QN;
    const _Float16* Qt = q16t + (size_t)b * HK * QN + (size_t)k0 * QN;
    int ar = t >> 2, aseg = t & 3;
    f32x4 acc[4][4] = {};
    for (int j0 = 0; j0 < QN; j0 += 32) {
        half8 a0 = *(const half8*)(Ab + (size_t)(ar +   0) * QN + j0 + aseg * 8);
        half8 a1 = *(const half8*)(Ab + (size_t)(ar +  64) * QN + j0 + aseg * 8);
        half8 a2 = *(const half8*)(Ab + (size_t)(ar + 128) * QN + j0 + aseg * 8);
        half8 a3 = *(const half8*)(Ab + (size_t)(ar + 192) * QN + j0 + aseg * 8);
        half8 bv = *(const half8*)(Qt + (size_t)ar * QN + j0 + aseg * 8);
        __syncthreads();
        *(half8*)&As[(ar +   0) * 32 + aseg * 8] = a0;
        *(half8*)&As[(ar +  64) * 32 + aseg * 8] = a1;
        *(half8*)&As[(ar + 128) * 32 + aseg * 8] = a2;
        *(half8*)&As[(ar + 192) * 32 + aseg * 8] = a3;
        *(half8*)&Bs[ar * 32 + aseg * 8] = bv;
        __syncthreads();
        half8 af[4], bf[4];
#pragma unroll
        for (int fi = 0; fi < 4; ++fi)
            af[fi] = *(const half8*)&As[(w * 64 + fi * 16 + r16) * 32 + quad * 8];
#pragma unroll
        for (int fj = 0; fj < 4; ++fj)
            bf[fj] = *(const half8*)&Bs[(fj * 16 + r16) * 32 + quad * 8];
#pragma unroll
        for (int fi = 0; fi < 4; ++fi)
#pragma unroll
            for (int fj = 0; fj < 4; ++fj)
                acc[fi][fj] = __builtin_amdgcn_mfma_f32_16x16x32_f16(
                    af[fi], bf[fj], acc[fi][fj], 0, 0, 0);
    }
    const _Float16* Vb = v16 + (size_t)b * VN * HK;
    float part[4] = {0.f, 0.f, 0.f, 0.f};
#pragma unroll
    for (int fi = 0; fi < 4; ++fi) {
#pragma unroll
        for (int r = 0; r < 4; ++r) {
            int i = w * 64 + fi * 16 + quad * 4 + r;
#pragma unroll
            for (int fj = 0; fj < 4; ++fj) {
                float vv = (float)Vb[(size_t)i * HK + k0 + fj * 16 + r16];
                part[fj] += acc[fi][fj][r] * vv;
            }
        }
    }
#pragma unroll
    for (int fj = 0; fj < 4; ++fj)
        red[w * 4 + quad][fj * 16 + r16] = part[fj];
    __syncthreads();
    if (t < 64) {
        float s = 0.f;
#pragma unroll
        for (int g = 0; g < 16; ++g) s += red[g][t];
        lk[b * HK + k0 + t] = s;
    }
}

// ---------------------------------------------------------------------------
// pool(k=3, sum) + BatchNorm (batch stats, biased var)
// ---------------------------------------------------------------------------
__global__ __launch_bounds__(256) void bn_kernel(
    const float* __restrict__ lk, const float* __restrict__ gamma,
    const float* __restrict__ beta, float* __restrict__ out) {
    int d = blockIdx.x * blockDim.x + threadIdx.x;
    if (d >= HDIM) return;
    float l[BB];
    float mu = 0.f;
#pragma unroll
    for (int b = 0; b < BB; ++b) {
        const float* p = lk + b * HK + 3 * d;
        float s = p[0] + p[1] + p[2];
        l[b] = s;
        mu += s;
    }
    mu *= (1.f / BB);
    float var = 0.f;
#pragma unroll
    for (int b = 0; b < BB; ++b) {
        float dd = l[b] - mu;
        var += dd * dd;
    }
    var *= (1.f / BB);
    float inv = rsqrtf(var + 1e-5f);
    float g = gamma[d], be = beta[d];
#pragma unroll
    for (int b = 0; b < BB; ++b)
        out[b * HDIM + d] = (l[b] - mu) * inv * g + be;
}

// ---------------------------------------------------------------------------
extern "C" void kernel_launch(void* const* d_in, const int* in_sizes, int n_in,
                              void* d_out, int out_size, void* d_ws, size_t ws_size,
                              hipStream_t stream) {
    const float* v  = (const float*)d_in[0];
    const float* q  = (const float*)d_in[1];
    const float* Wv = (const float*)d_in[2];
    const float* bv = (const float*)d_in[3];
    const float* Wq = (const float*)d_in[4];
    const float* bq = (const float*)d_in[5];
    const float* hm = (const float*)d_in[6];
    const float* hb = (const float*)d_in[7];
    const float* gamma = (const float*)d_in[8];
    const float* beta  = (const float*)d_in[9];

    float* out_logits = (float*)d_out;
    float* out_att    = out_logits + BB * HDIM;

    // workspace layout (f16 elements unless noted)
    _Float16* h = (_Float16*)d_ws;
    _Float16* v16   = h;                                   // 16*256*1536
    _Float16* q16   = v16 + (size_t)BB * VN * HK;          // 16*256*1536
    _Float16* q16t  = q16 + (size_t)BB * QN * HK;          // 16*1536*256
    _Float16* A16   = q16t + (size_t)BB * HK * QN;         // 16*256*256
    _Float16* v16in = A16 + (size_t)BB * VN * QN;          // 16*256*512
    _Float16* q16in = v16in + (size_t)BB * VN * VD;        // 16*256*768
    _Float16* Wv16  = q16in + (size_t)BB * QN * QD;        // 1536*512
    _Float16* Wq16  = Wv16 + (size_t)HK * VD;              // 1536*768
    _Float16* hs16  = Wq16 + (size_t)HK * QD;              // 9*1536
    float* lk = (float*)(hs16 + 9 * HK + 8);               // 16*1536 f32
    float* vz = lk + BB * HK;
    float* qz = vz + BB * VN;

    // 1. fused conversions + masks
    conv_mask2<<<dim3(BB * VN / 4, 2), 256, 0, stream>>>(v, q, v16in, q16in, vz, qz);
    conv_w2<<<dim3((HK * QD / 4 + 255) / 256, 2), 256, 0, stream>>>(
        Wv, Wv16, HK * VD / 4, Wq, Wq16, HK * QD / 4);
    conv_hm9<<<(HK + 255) / 256, 256, 0, stream>>>(hm, hs16);

    // 2. projections -> v16, q16 (f16, relu), double-buffered pipeline
    proj_db<<<dim3(HK / 64, BB * VN / 64), 128, 0, stream>>>(v16in, Wv16, bv, v16, VD);
    proj_db<<<dim3(HK / 64, BB * QN / 64), 128, 0, stream>>>(q16in, Wq16, bq, q16, QD);

    // 3. att heads 0..7 -> d_out; head 8 -> A16 (3 heads/wave, dbuf pipeline)
    att_db<<<dim3(QN / 64, VN / 64, BB * 3), 128, 0, stream>>>(
        v16, q16, hs16, hb, vz, qz, out_att, A16);

    // 4. q16t = transpose(q16)
    transpose_q16<<<dim3(HK / 64, QN / 32, BB), 256, 0, stream>>>(q16, q16t);

    // 5. lk = v16 . (A16 @ q16t^T)   fused
    t_lk_mfma<<<dim3(HK / 64, BB), 256, 0, stream>>>(A16, q16t, v16, lk);

    // 6. pool + batchnorm
    bn_kernel<<<dim3((HDIM + 255) / 256), 256, 0, stream>>>(lk, gamma, beta, out_logits);
}

// Round 9
// 202.984 us; speedup vs baseline: 1.2415x; 1.2415x over previous
//
#include <hip/hip_runtime.h>
#include <math.h>

#define BB    16
#define VN    256
#define QN    256
#define VD    512
#define QD    768
#define HK    1536
#define HDIM  512

typedef _Float16 half8 __attribute__((ext_vector_type(8)));
typedef _Float16 half4 __attribute__((ext_vector_type(4)));
typedef float f32x4 __attribute__((ext_vector_type(4)));

// ---------------------------------------------------------------------------
// fused fp32->f16 conversion + zero-row mask for BOTH v and q in one launch.
// blockIdx.y: 0 -> v (D=512), 1 -> q (D=768). One wave per row, 4 rows/block.
// ---------------------------------------------------------------------------
__global__ __launch_bounds__(256) void conv_mask2(
    const float* __restrict__ v, const float* __restrict__ q,
    _Float16* __restrict__ v16, _Float16* __restrict__ q16,
    float* __restrict__ vz, float* __restrict__ qz) {
    int which = blockIdx.y;
    const float* src = which ? q : v;
    _Float16* dst = which ? q16 : v16;
    float* outz = which ? qz : vz;
    int D = which ? QD : VD;
    int w = threadIdx.x >> 6, ln = threadIdx.x & 63;
    int row = blockIdx.x * 4 + w;
    const float* p = src + (size_t)row * D;
    _Float16* d = dst + (size_t)row * D;
    float s = 0.f;
    for (int c = ln * 4; c < D; c += 256) {
        float4 x = *(const float4*)(p + c);
        s += fabsf(x.x) + fabsf(x.y) + fabsf(x.z) + fabsf(x.w);
        half4 hh = {(_Float16)x.x, (_Float16)x.y, (_Float16)x.z, (_Float16)x.w};
        *(half4*)(d + c) = hh;
    }
    for (int off = 32; off > 0; off >>= 1) s += __shfl_down(s, off);
    if (ln == 0) outz[row] = (s == 0.f) ? 1.f : 0.f;
}

// ---------------------------------------------------------------------------
// Weight + hm conversions in one launch: y=0 Wv, y=1 Wq, y=2 hm->hs16[9]
// ---------------------------------------------------------------------------
__global__ __launch_bounds__(256) void conv_w3(
    const float* __restrict__ Wv, _Float16* __restrict__ Wv16, int n4v,
    const float* __restrict__ Wq, _Float16* __restrict__ Wq16, int n4q,
    const float* __restrict__ hm, _Float16* __restrict__ hs16) {
    if (blockIdx.y == 2) {
        int k = blockIdx.x * 256 + threadIdx.x;
        if (k >= HK) return;
        float s = 0.f;
#pragma unroll
        for (int h = 0; h < 8; ++h) {
            float x = hm[h * HK + k];
            s += x;
            hs16[h * HK + k] = (_Float16)x;
        }
        hs16[8 * HK + k] = (_Float16)s;
        return;
    }
    const float* src = blockIdx.y ? Wq : Wv;
    _Float16* dst = blockIdx.y ? Wq16 : Wv16;
    int n4 = blockIdx.y ? n4q : n4v;
    int i = blockIdx.x * 256 + threadIdx.x;
    if (i < n4) {
        float4 x = ((const float4*)src)[i];
        half4 h = {(_Float16)x.x, (_Float16)x.y, (_Float16)x.z, (_Float16)x.w};
        ((half4*)dst)[i] = h;
    }
}

// ---------------------------------------------------------------------------
// Projection GEMM (R7-proven): C16[m,n] = (f16) relu(sum_k A[m,k]*W[n,k]+b[n])
// Block 64m x 64n, 128 thr = 2 waves (wave 32m x 64n), BK=64.
// Single-buffer, reg-prefetch, XOR-swizzled LDS.
// ---------------------------------------------------------------------------
__global__ __launch_bounds__(128) void proj_lds(
    const _Float16* __restrict__ Ain, const _Float16* __restrict__ W16,
    const float* __restrict__ bias, _Float16* __restrict__ C16, int K) {
    __shared__ _Float16 As[64 * 64];
    __shared__ _Float16 Bs[64 * 64];
    int m0 = blockIdx.y * 64, n0 = blockIdx.x * 64;
    int t = threadIdx.x;
    int w = t >> 6, ln = t & 63, quad = ln >> 4, r16 = ln & 15;
    int arow = t >> 3, aseg = t & 7;
    int sg = aseg ^ (arow & 7);
    const _Float16* ApG = Ain + (size_t)(m0 + arow) * K + aseg * 8;
    const _Float16* BpG = W16 + (size_t)(n0 + arow) * K + aseg * 8;
    half8 ra[4], rb[4];
#pragma unroll
    for (int c = 0; c < 4; ++c) {
        ra[c] = *(const half8*)(ApG + (size_t)c * 16 * K);
        rb[c] = *(const half8*)(BpG + (size_t)c * 16 * K);
    }
    f32x4 acc[2][4] = {};
    for (int k0 = 0; k0 < K; k0 += 64) {
        __syncthreads();
#pragma unroll
        for (int c = 0; c < 4; ++c) {
            *(half8*)&As[(c * 16 + arow) * 64 + sg * 8] = ra[c];
            *(half8*)&Bs[(c * 16 + arow) * 64 + sg * 8] = rb[c];
        }
        __syncthreads();
        if (k0 + 64 < K) {
#pragma unroll
            for (int c = 0; c < 4; ++c) {
                ra[c] = *(const half8*)(ApG + (size_t)c * 16 * K + k0 + 64);
                rb[c] = *(const half8*)(BpG + (size_t)c * 16 * K + k0 + 64);
            }
        }
#pragma unroll
        for (int kc = 0; kc < 2; ++kc) {
            half8 af[2], bf[4];
#pragma unroll
            for (int fi = 0; fi < 2; ++fi) {
                int rl = w * 32 + fi * 16 + r16;
                af[fi] = *(const half8*)&As[rl * 64 + ((kc * 4 + quad) ^ (rl & 7)) * 8];
            }
#pragma unroll
            for (int fj = 0; fj < 4; ++fj) {
                int rl = fj * 16 + r16;
                bf[fj] = *(const half8*)&Bs[rl * 64 + ((kc * 4 + quad) ^ (rl & 7)) * 8];
            }
#pragma unroll
            for (int fi = 0; fi < 2; ++fi)
#pragma unroll
                for (int fj = 0; fj < 4; ++fj)
                    acc[fi][fj] = __builtin_amdgcn_mfma_f32_16x16x32_f16(
                        af[fi], bf[fj], acc[fi][fj], 0, 0, 0);
        }
    }
#pragma unroll
    for (int fi = 0; fi < 2; ++fi) {
#pragma unroll
        for (int r = 0; r < 4; ++r) {
            int m = m0 + w * 32 + fi * 16 + quad * 4 + r;
#pragma unroll
            for (int fj = 0; fj < 4; ++fj) {
                int n = n0 + fj * 16 + r16;
                float x = acc[fi][fj][r] + bias[n];
                C16[(size_t)m * HK + n] = (_Float16)fmaxf(x, 0.f);
            }
        }
    }
}

// ---------------------------------------------------------------------------
// att: 3 heads per wave, R7 K-loop, but 4 waves/block (256 thr).
// Block 64i x 64j; wave (wi,wj) covers 32i x 32j x 3 heads -> 12 waves/CU.
// z = b*3 + head_group. h<8 -> att_out fp32; h==8 -> A16 f16.
// ---------------------------------------------------------------------------
__global__ __launch_bounds__(256) void att4(
    const _Float16* __restrict__ v16, const _Float16* __restrict__ q16,
    const _Float16* __restrict__ hs16, const float* __restrict__ hb,
    const float* __restrict__ vz, const float* __restrict__ qz,
    float* __restrict__ att_out, _Float16* __restrict__ A16) {
    __shared__ _Float16 As[64 * 64];
    __shared__ _Float16 Bs[64 * 64];
    __shared__ _Float16 Hl[3 * HK];
    int z = blockIdx.z;
    int b = z / 3, hg = z - b * 3;
    int h0 = hg * 3;
    int i0 = blockIdx.y * 64, j0 = blockIdx.x * 64;
    int t = threadIdx.x;
    int w = t >> 6, ln = t & 63, quad = ln >> 4, r16 = ln & 15;
    int wi = w & 1, wj = w >> 1;
    int arow = t >> 3, aseg = t & 7;     // arow 0..31
    int sg = aseg ^ (arow & 7);
    // stage hm rows h0..h0+2 (9 KB), fenced by the first loop barrier
    for (int u = t * 8; u < 3 * HK; u += 256 * 8)
        *(half8*)&Hl[u] = *(const half8*)(hs16 + (size_t)h0 * HK + u);
    const _Float16* ApG = v16 + (size_t)b * VN * HK + (size_t)(i0 + arow) * HK + aseg * 8;
    const _Float16* BpG = q16 + (size_t)b * QN * HK + (size_t)(j0 + arow) * HK + aseg * 8;
    half8 ra[2], rb[2];
#pragma unroll
    for (int c = 0; c < 2; ++c) {
        ra[c] = *(const half8*)(ApG + (size_t)c * 32 * HK);
        rb[c] = *(const half8*)(BpG + (size_t)c * 32 * HK);
    }
    f32x4 acc[3][2][2] = {};
    for (int it = 0; it < 24; ++it) {
        __syncthreads();
#pragma unroll
        for (int c = 0; c < 2; ++c) {
            *(half8*)&As[(c * 32 + arow) * 64 + sg * 8] = ra[c];
            *(half8*)&Bs[(c * 32 + arow) * 64 + sg * 8] = rb[c];
        }
        __syncthreads();
        if (it + 1 < 24) {
            int kn = (it + 1) * 64;
#pragma unroll
            for (int c = 0; c < 2; ++c) {
                ra[c] = *(const half8*)(ApG + (size_t)c * 32 * HK + kn);
                rb[c] = *(const half8*)(BpG + (size_t)c * 32 * HK + kn);
            }
        }
        int kb = it * 64;
#pragma unroll
        for (int kc = 0; kc < 2; ++kc) {
            half8 af[2], bf[2];
#pragma unroll
            for (int fi = 0; fi < 2; ++fi) {
                int rl = wi * 32 + fi * 16 + r16;
                af[fi] = *(const half8*)&As[rl * 64 + ((kc * 4 + quad) ^ (rl & 7)) * 8];
            }
#pragma unroll
            for (int fj = 0; fj < 2; ++fj) {
                int rl = wj * 32 + fj * 16 + r16;
                bf[fj] = *(const half8*)&Bs[rl * 64 + ((kc * 4 + quad) ^ (rl & 7)) * 8];
            }
#pragma unroll
            for (int hh = 0; hh < 3; ++hh) {
                half8 hmv = *(const half8*)&Hl[hh * HK + kb + (kc * 4 + quad) * 8];
#pragma unroll
                for (int fi = 0; fi < 2; ++fi) {
                    half8 am = af[fi] * hmv;
#pragma unroll
                    for (int fj = 0; fj < 2; ++fj)
                        acc[hh][fi][fj] = __builtin_amdgcn_mfma_f32_16x16x32_f16(
                            am, bf[fj], acc[hh][fi][fj], 0, 0, 0);
                }
            }
        }
    }
#pragma unroll
    for (int hh = 0; hh < 3; ++hh) {
        int h = h0 + hh;
        float hbv;
        if (h < 8) {
            hbv = hb[h];
        } else {
            hbv = 0.f;
#pragma unroll
            for (int x = 0; x < 8; ++x) hbv += hb[x];
        }
        if (h < 8) {
            float* outb = att_out + ((size_t)(b * 8 + h)) * VN * QN;
#pragma unroll
            for (int fi = 0; fi < 2; ++fi) {
#pragma unroll
                for (int r = 0; r < 4; ++r) {
                    int i = i0 + wi * 32 + fi * 16 + quad * 4 + r;
                    float vm = vz[b * VN + i];
#pragma unroll
                    for (int fj = 0; fj < 2; ++fj) {
                        int j = j0 + wj * 32 + fj * 16 + r16;
                        float x = acc[hh][fi][fj][r] + hbv;
                        if (vm != 0.f || qz[b * QN + j] != 0.f) x = -INFINITY;
                        outb[(size_t)i * QN + j] = x;
                    }
                }
            }
        } else {
            _Float16* Ab = A16 + (size_t)b * VN * QN;
#pragma unroll
            for (int fi = 0; fi < 2; ++fi) {
#pragma unroll
                for (int r = 0; r < 4; ++r) {
                    int i = i0 + wi * 32 + fi * 16 + quad * 4 + r;
                    float vm = vz[b * VN + i];
#pragma unroll
                    for (int fj = 0; fj < 2; ++fj) {
                        int j = j0 + wj * 32 + fj * 16 + r16;
                        float x = acc[hh][fi][fj][r] + hbv;
                        if (vm != 0.f || qz[b * QN + j] != 0.f) x = -INFINITY;
                        Ab[(size_t)i * QN + j] = (_Float16)x;
                    }
                }
            }
        }
    }
}

// ---------------------------------------------------------------------------
// q16t[b][k][j] = q16[b][j][k]  (per-batch transpose, 32j x 64k LDS tiles)
// ---------------------------------------------------------------------------
__global__ __launch_bounds__(256) void transpose_q16(const _Float16* __restrict__ q16,
                                                     _Float16* __restrict__ q16t) {
    __shared__ _Float16 Ls[32][72];
    int b = blockIdx.z;
    int k0 = blockIdx.x * 64, j0 = blockIdx.y * 32;
    int t = threadIdx.x;
    const _Float16* src = q16 + (size_t)b * QN * HK;
    int tj = t >> 3, tk = (t & 7) * 8;
    half8 vv = *(const half8*)(src + (size_t)(j0 + tj) * HK + k0 + tk);
#pragma unroll
    for (int e = 0; e < 8; ++e) Ls[tj][tk + e] = vv[e];
    __syncthreads();
    int ok = t >> 2, oj = (t & 3) * 8;
    half8 ov;
#pragma unroll
    for (int e = 0; e < 8; ++e) ov[e] = Ls[oj + e][ok];
    *(half8*)(q16t + (size_t)b * HK * QN + (size_t)(k0 + ok) * QN + j0 + oj) = ov;
}

// ---------------------------------------------------------------------------
// lk[b,k] = sum_i v16[b,i,k] * (sum_j A16[b,i,j] * q16t[b,k,j])
// ---------------------------------------------------------------------------
__global__ __launch_bounds__(256) void t_lk_mfma(
    const _Float16* __restrict__ A16, const _Float16* __restrict__ q16t,
    const _Float16* __restrict__ v16, float* __restrict__ lk) {
    __shared__ _Float16 As[256 * 32];
    __shared__ _Float16 Bs[64 * 32];
    __shared__ float red[16][64];
    int b = blockIdx.y;
    int k0 = blockIdx.x * 64;
    int t = threadIdx.x;
    int w = t >> 6, ln = t & 63, quad = ln >> 4, r16 = ln & 15;
    const _Float16* Ab = A16 + (size_t)b * VN * QN;
    const _Float16* Qt = q16t + (size_t)b * HK * QN + (size_t)k0 * QN;
    int ar = t >> 2, aseg = t & 3;
    f32x4 acc[4][4] = {};
    for (int j0 = 0; j0 < QN; j0 += 32) {
        half8 a0 = *(const half8*)(Ab + (size_t)(ar +   0) * QN + j0 + aseg * 8);
        half8 a1 = *(const half8*)(Ab + (size_t)(ar +  64) * QN + j0 + aseg * 8);
        half8 a2 = *(const half8*)(Ab + (size_t)(ar + 128) * QN + j0 + aseg * 8);
        half8 a3 = *(const half8*)(Ab + (size_t)(ar + 192) * QN + j0 + aseg * 8);
        half8 bv = *(const half8*)(Qt + (size_t)ar * QN + j0 + aseg * 8);
        __syncthreads();
        *(half8*)&As[(ar +   0) * 32 + aseg * 8] = a0;
        *(half8*)&As[(ar +  64) * 32 + aseg * 8] = a1;
        *(half8*)&As[(ar + 128) * 32 + aseg * 8] = a2;
        *(half8*)&As[(ar + 192) * 32 + aseg * 8] = a3;
        *(half8*)&Bs[ar * 32 + aseg * 8] = bv;
        __syncthreads();
        half8 af[4], bf[4];
#pragma unroll
        for (int fi = 0; fi < 4; ++fi)
            af[fi] = *(const half8*)&As[(w * 64 + fi * 16 + r16) * 32 + quad * 8];
#pragma unroll
        for (int fj = 0; fj < 4; ++fj)
            bf[fj] = *(const half8*)&Bs[(fj * 16 + r16) * 32 + quad * 8];
#pragma unroll
        for (int fi = 0; fi < 4; ++fi)
#pragma unroll
            for (int fj = 0; fj < 4; ++fj)
                acc[fi][fj] = __builtin_amdgcn_mfma_f32_16x16x32_f16(
                    af[fi], bf[fj], acc[fi][fj], 0, 0, 0);
    }
    const _Float16* Vb = v16 + (size_t)b * VN * HK;
    float part[4] = {0.f, 0.f, 0.f, 0.f};
#pragma unroll
    for (int fi = 0; fi < 4; ++fi) {
#pragma unroll
        for (int r = 0; r < 4; ++r) {
            int i = w * 64 + fi * 16 + quad * 4 + r;
#pragma unroll
            for (int fj = 0; fj < 4; ++fj) {
                float vv = (float)Vb[(size_t)i * HK + k0 + fj * 16 + r16];
                part[fj] += acc[fi][fj][r] * vv;
            }
        }
    }
#pragma unroll
    for (int fj = 0; fj < 4; ++fj)
        red[w * 4 + quad][fj * 16 + r16] = part[fj];
    __syncthreads();
    if (t < 64) {
        float s = 0.f;
#pragma unroll
        for (int g = 0; g < 16; ++g) s += red[g][t];
        lk[b * HK + k0 + t] = s;
    }
}

// ---------------------------------------------------------------------------
// pool(k=3, sum) + BatchNorm (batch stats, biased var)
// ---------------------------------------------------------------------------
__global__ __launch_bounds__(256) void bn_kernel(
    const float* __restrict__ lk, const float* __restrict__ gamma,
    const float* __restrict__ beta, float* __restrict__ out) {
    int d = blockIdx.x * blockDim.x + threadIdx.x;
    if (d >= HDIM) return;
    float l[BB];
    float mu = 0.f;
#pragma unroll
    for (int b = 0; b < BB; ++b) {
        const float* p = lk + b * HK + 3 * d;
        float s = p[0] + p[1] + p[2];
        l[b] = s;
        mu += s;
    }
    mu *= (1.f / BB);
    float var = 0.f;
#pragma unroll
    for (int b = 0; b < BB; ++b) {
        float dd = l[b] - mu;
        var += dd * dd;
    }
    var *= (1.f / BB);
    float inv = rsqrtf(var + 1e-5f);
    float g = gamma[d], be = beta[d];
#pragma unroll
    for (int b = 0; b < BB; ++b)
        out[b * HDIM + d] = (l[b] - mu) * inv * g + be;
}

// ---------------------------------------------------------------------------
extern "C" void kernel_launch(void* const* d_in, const int* in_sizes, int n_in,
                              void* d_out, int out_size, void* d_ws, size_t ws_size,
                              hipStream_t stream) {
    const float* v  = (const float*)d_in[0];
    const float* q  = (const float*)d_in[1];
    const float* Wv = (const float*)d_in[2];
    const float* bv = (const float*)d_in[3];
    const float* Wq = (const float*)d_in[4];
    const float* bq = (const float*)d_in[5];
    const float* hm = (const float*)d_in[6];
    const float* hb = (const float*)d_in[7];
    const float* gamma = (const float*)d_in[8];
    const float* beta  = (const float*)d_in[9];

    float* out_logits = (float*)d_out;
    float* out_att    = out_logits + BB * HDIM;

    // workspace layout (f16 elements unless noted)
    _Float16* h = (_Float16*)d_ws;
    _Float16* v16   = h;                                   // 16*256*1536
    _Float16* q16   = v16 + (size_t)BB * VN * HK;          // 16*256*1536
    _Float16* q16t  = q16 + (size_t)BB * QN * HK;          // 16*1536*256
    _Float16* A16   = q16t + (size_t)BB * HK * QN;         // 16*256*256
    _Float16* v16in = A16 + (size_t)BB * VN * QN;          // 16*256*512
    _Float16* q16in = v16in + (size_t)BB * VN * VD;        // 16*256*768
    _Float16* Wv16  = q16in + (size_t)BB * QN * QD;        // 1536*512
    _Float16* Wq16  = Wv16 + (size_t)HK * VD;              // 1536*768
    _Float16* hs16  = Wq16 + (size_t)HK * QD;              // 9*1536
    float* lk = (float*)(hs16 + 9 * HK + 8);               // 16*1536 f32
    float* vz = lk + BB * HK;
    float* qz = vz + BB * VN;

    // 1. fused conversions + masks (2 launches)
    conv_mask2<<<dim3(BB * VN / 4, 2), 256, 0, stream>>>(v, q, v16in, q16in, vz, qz);
    conv_w3<<<dim3((HK * QD / 4 + 255) / 256, 3), 256, 0, stream>>>(
        Wv, Wv16, HK * VD / 4, Wq, Wq16, HK * QD / 4, hm, hs16);

    // 2. projections -> v16, q16 (f16, relu), R7 single-buffer pipeline
    proj_lds<<<dim3(HK / 64, BB * VN / 64), 128, 0, stream>>>(v16in, Wv16, bv, v16, VD);
    proj_lds<<<dim3(HK / 64, BB * QN / 64), 128, 0, stream>>>(q16in, Wq16, bq, q16, QD);

    // 3. att heads 0..7 -> d_out; head 8 -> A16 (3 heads/wave, 4 waves/block)
    att4<<<dim3(QN / 64, VN / 64, BB * 3), 256, 0, stream>>>(
        v16, q16, hs16, hb, vz, qz, out_att, A16);

    // 4. q16t = transpose(q16)
    transpose_q16<<<dim3(HK / 64, QN / 32, BB), 256, 0, stream>>>(q16, q16t);

    // 5. lk = v16 . (A16 @ q16t^T)   fused
    t_lk_mfma<<<dim3(HK / 64, BB), 256, 0, stream>>>(A16, q16t, v16, lk);

    // 6. pool + batchnorm
    bn_kernel<<<dim3((HDIM + 255) / 256), 256, 0, stream>>>(lk, gamma, beta, out_logits);
}